// Round 13
// baseline (97.603 us; speedup 1.0000x reference)
//
#include <hip/hip_runtime.h>

typedef __bf16 bf16;
typedef __bf16 bf16x8 __attribute__((ext_vector_type(8)));
typedef __bf16 bf16x4 __attribute__((ext_vector_type(4)));
typedef float f32x4 __attribute__((ext_vector_type(4)));
typedef unsigned int u32;

#define NB    2048
#define NM    26
#define NJP   27      // 26 K-chunks + 1 zero pad (unconditional prefetch)

// ---------------- prep: frag-linear weight tiles (w1q + w2t2) ----------------
// w1q: [q(4)][c(27)][32x32 tile]; in a tile, elem (r=ni*16+lr, col=lq*8+el)
// at ni*512 + lq*128 + lr*8 + el (tile = 1024 elems). h = q*32 + r, i = col.
// w2t2: [cs2(2)][kc(130)][64x32 tile] as before.
// 110,592 + 532,480 = 643,072 elems = 628 blocks * 256 * 4 exactly.
__global__ __launch_bounds__(256) void prep_all(
    const float* __restrict__ W1, const float* __restrict__ W2,
    bf16* __restrict__ w1q, bf16* __restrict__ w2t2)
{
  const int bid = blockIdx.x, t = threadIdx.x;
  #pragma unroll
  for (int g = 0; g < 4; ++g) {
    int ge = g*160768 + bid*256 + t;
    if (ge < 110592) {                    // w1q tiles, frag-linear 32-row
      int e = ge;
      int el = e & 7, lr = (e >> 3) & 15, lq = (e >> 7) & 3, ni = (e >> 9) & 1;
      int rest = e >> 10;                 // [0, 108) = q*27 + c
      int c = rest % NJP, q = rest / NJP;
      int h = q*32 + ni*16 + lr;
      int i = lq*8 + el;
      float v = (i < NM && c < NM) ? W1[h*(NM*NM) + i*NM + c] : 0.f;
      w1q[e] = (bf16)v;
    } else {                              // w2t2 tiles [cs2(2)][kc(130)], frag-linear
      int e = ge - 110592;                // flatK = kc*32 + c  (kc=i, c=j)
      int el = e & 7, lr = (e >> 3) & 15, lq = (e >> 7) & 3, ni = (e >> 9) & 3;
      int rest = e >> 11;                 // [0, 260)
      int kc = rest % 130, cs_idx = rest / 130;
      int h = cs_idx*64 + ni*16 + lr;
      int c = lq*8 + el;
      float v = (kc < 128 && c < NM) ? W2[h*(128*NM) + kc*NM + c] : 0.f;
      w2t2[e] = (bf16)v;
    }
  }
}

// layer-1 K-chunk step (quarter: ni<2, chunk stride 1024): scalars (f32) +
// B-frags prefetched 1 ahead; compute chunk J for BOTH batches from CUR.
#define STEP(CUR, NXT, J) do {                                                 \
  { int jn = ((J)+1 > 25) ? 25 : (J)+1;  /* chunk-26 weights are zero */       \
    scf[NXT][0][0] = spw0[jn*32];  scf[NXT][0][1] = spw0[jn*32 + 16];          \
    scf[NXT][1][0] = spw1[jn*32];  scf[NXT][1][1] = spw1[jn*32 + 16]; }        \
  _Pragma("unroll")                                                            \
  for (int ni = 0; ni < 2; ++ni)                                               \
    B[NXT][ni] = *(const bf16x8*)(tb + (long)((J)+1)*1024 + ni*512);           \
  _Pragma("unroll")                                                            \
  for (int bb = 0; bb < 2; ++bb)                                               \
    _Pragma("unroll")                                                          \
    for (int mi = 0; mi < 2; ++mi) {                                           \
      bf16x8 af;                                                               \
      _Pragma("unroll")                                                        \
      for (int e = 0; e < 8; ++e)                                              \
        af[e] = (bf16)(xf32[bb][mi][e] * scf[CUR][bb][mi]);                    \
      _Pragma("unroll")                                                        \
      for (int ni = 0; ni < 2; ++ni)                                           \
        acc[bb][mi][ni] = __builtin_amdgcn_mfma_f32_16x16x32_bf16(af,          \
                                    B[CUR][ni], acc[bb][mi][ni], 0, 0, 0);     \
    }                                                                          \
} while (0)

// mini-gemm K-step: A (LDS, ping-pong) + B (w2t2 L2, 4-deep cyclic, literal
// phases). Tail prefetches read ldsU pad slots / mapped w2t2 overrun (unused).
#define STEPM(CA, NA, KL, Q) do {                                              \
  Af[NA] = *(const bf16x8*)&ldsU[(((KL)+1)*4 + lq)*72 + lr*8];                 \
  Bf[((Q)+3)&3][0] = *(const bf16x8*)(Bb0 + (long)((KL)+3)*2048);              \
  Bf[((Q)+3)&3][1] = *(const bf16x8*)(Bb1 + (long)((KL)+3)*2048);              \
  _Pragma("unroll")                                                            \
  for (int ht = 0; ht < 2; ++ht)                                               \
    acc2[ht] = __builtin_amdgcn_mfma_f32_16x16x32_bf16(Af[CA], Bf[(Q)][ht],    \
                                                       acc2[ht], 0, 0, 0);     \
} while (0)

// ---------------- fused: layer 1 + G (LDS) + layer-2 mini-gemm ---------------
// Block = 8 batches x one i-QUARTER [h0, h0+32). Grid 1024 = 4 blocks/CU
// resident (4 waves/SIMD — 2x r12's TLP). LDS = 19.6 KB union:
// phase A = 4 wave-private x1^T tiles [32][36]; phase B = G A-tile
// ldsG[k8(128 + 8 pad)][b(8)][8] (slot stride 72). G outputs carried across
// the repurposing barrier in 16 packed VGPRs. Mini-gemm: out2[8b x 32h] over
// K=1024 (this quarter), A from LDS, B 4-deep from w2t2. q==0 folds bias.
__global__ __launch_bounds__(256, 4) void cinfuse(
    const float* __restrict__ in, const bf16* __restrict__ w1q,
    const bf16* __restrict__ w2t2, const float* __restrict__ b1,
    const float* __restrict__ b2, float* __restrict__ out)
{
  __shared__ __align__(16) bf16 ldsU[136*72];     // 19,584 B (union, see above)
  const int t = threadIdx.x, bid = blockIdx.x;
  const int lane = t & 63, w = t >> 6;
  const int lr = lane & 15, lq = lane >> 4;
  const int fo = lq*128 + lr*8;
  const int q = bid & 3, h0 = q*32;               // i-quarter
  const int grp = bid >> 2;                       // 0..255, 8 batches each
  const int bw0 = grp*8 + w*2;                    // this wave's batches bw0, bw0+1

  const float* bin0 = in + (long)bw0*(NM*32);
  const float* bin1 = bin0 + NM*32;
  const float* spw0 = bin0 + lr;                  // + j*32 + mi*16 (k = mi*16+lr)
  const float* spw1 = bin1 + lr;

  // x0 A-frags in f32: xf32[bb][mi][e] = x0[bw0+bb][j=lq*8+e][k=mi*16+lr]
  float xf32[2][2][8];
  #pragma unroll
  for (int bb = 0; bb < 2; ++bb) {
    const float* bin = bb ? bin1 : bin0;
    #pragma unroll
    for (int mi = 0; mi < 2; ++mi)
      #pragma unroll
      for (int e = 0; e < 8; ++e) {
        int j = lq*8 + e;
        xf32[bb][mi][e] = (j < NM) ? bin[j*32 + mi*16 + lr] : 0.f;
      }
  }

  f32x4 acc[2][2][2];
  #pragma unroll
  for (int bb=0; bb<2; ++bb)
    #pragma unroll
    for (int mi=0; mi<2; ++mi)
      #pragma unroll
      for (int ni=0; ni<2; ++ni) acc[bb][mi][ni] = {0.f,0.f,0.f,0.f};

  const bf16* tb = w1q + (long)q*NJP*1024 + fo;

  float scf[2][2][2];
  bf16x8 B[2][2];
  #pragma unroll
  for (int ni = 0; ni < 2; ++ni)
    B[0][ni] = *(const bf16x8*)(tb + ni*512);     // chunk 0
  scf[0][0][0] = spw0[0];  scf[0][0][1] = spw0[16];
  scf[0][1][0] = spw1[0];  scf[0][1][1] = spw1[16];

  for (int jj = 0; jj < 13; ++jj) {
    STEP(0, 1, 2*jj);
    STEP(1, 0, 2*jj + 1);
  }

  float bias[2];
  #pragma unroll
  for (int ni=0; ni<2; ++ni) bias[ni] = b1[h0 + ni*16 + lr];

  bf16* T = &ldsU[w*1152];                        // wave-private x1^T [32][36]

  bf16x4 pk[2][2][2];                             // G outputs, carried (16 VGPR)

  #pragma unroll
  for (int bb = 0; bb < 2; ++bb) {
    const int bw = bw0 + bb;
    const float* bin = bb ? bin1 : bin0;

    // out[bw][h0:h0+32] = k-sum of x1 + 32*bias
    #pragma unroll
    for (int ni=0; ni<2; ++ni) {
      float vv = 0.f;
      #pragma unroll
      for (int mi=0; mi<2; ++mi)
        #pragma unroll
        for (int r=0; r<4; ++r) vv += acc[bb][mi][ni][r];
      vv += __shfl_xor(vv, 16, 64);
      vv += __shfl_xor(vv, 32, 64);
      if (lq == 0) out[bw*256 + h0 + ni*16 + lr] = vv + 32.0f * bias[ni];
    }

    // x1 (C-layout) -> wave-private x1^T tile [i_local][k], row stride 36
    #pragma unroll
    for (int mi=0; mi<2; ++mi)
      #pragma unroll
      for (int ni=0; ni<2; ++ni) {
        bf16x4 p;
        #pragma unroll
        for (int r=0; r<4; ++r) p[r] = (bf16)(acc[bb][mi][ni][r] + bias[ni]);
        *(bf16x4*)&T[(ni*16+lr)*36 + mi*16 + lq*4] = p;
      }
    // same-wave DS ordering: reads below see this wave's writes

    // B-frags: x0[j][k] from in
    bf16x8 bg[2];
    #pragma unroll
    for (int nt = 0; nt < 2; ++nt) {
      int j = nt*16 + lr;
      bf16x8 vv;
      #pragma unroll
      for (int e=0; e<8; ++e) vv[e] = (bf16)0.f;
      if (j < NM) {
        const float* src = bin + j*32 + lq*8;
        f32x4 a = *(const f32x4*)src, c = *(const f32x4*)(src+4);
        #pragma unroll
        for (int e=0; e<4; ++e) { vv[e] = (bf16)a[e]; vv[4+e] = (bf16)c[e]; }
      }
      bg[nt] = vv;
    }
    // swapped G-MFMAs (read T now; write ldsG after the barrier)
    #pragma unroll
    for (int mt = 0; mt < 2; ++mt) {
      bf16x8 ag = *(const bf16x8*)&T[(mt*16+lr)*36 + lq*8];
      #pragma unroll
      for (int nt = 0; nt < 2; ++nt) {
        f32x4 z = {0.f,0.f,0.f,0.f};
        f32x4 g = __builtin_amdgcn_mfma_f32_16x16x32_bf16(bg[nt], ag, z, 0, 0, 0);
        // lane holds G[bw][i_loc=mt*16+lr][j=nt*16+lq*4+r]
        #pragma unroll
        for (int r = 0; r < 4; ++r) pk[bb][mt][nt][r] = (bf16)g[r];
      }
    }
  }

  __syncthreads();            // all x1^T reads done -> ldsU becomes the G-tile

  #pragma unroll
  for (int bb = 0; bb < 2; ++bb) {
    const int bloc = w*2 + bb;                    // block-local batch 0..7
    #pragma unroll
    for (int mt = 0; mt < 2; ++mt)
      #pragma unroll
      for (int nt = 0; nt < 2; ++nt) {
        const int kh = (mt*16 + lr)*4 + nt*2 + (lq >> 1);   // flatK_loc >> 3
        *(bf16x4*)&ldsU[kh*72 + bloc*8 + (lq & 1)*4] = pk[bb][mt][nt];
      }
  }

  __syncthreads();                                // all 8 batches' G in ldsU

  // ---- mini-gemm: wave w owns h-tiles {w*2, w*2+1}; K = 1024 (32 kc) ----
  const int ht0 = w*2, ht1 = w*2 + 1;
  const bf16* Bb0 = w2t2 + ((long)(ht0 >> 2)*130 + q*32)*2048 + (ht0 & 3)*512 + fo;
  const bf16* Bb1 = w2t2 + ((long)(ht1 >> 2)*130 + q*32)*2048 + (ht1 & 3)*512 + fo;

  f32x4 acc2[2];
  acc2[0] = {0.f,0.f,0.f,0.f};  acc2[1] = {0.f,0.f,0.f,0.f};

  bf16x8 Af[2], Bf[4][2];
  Af[0] = *(const bf16x8*)&ldsU[lq*72 + lr*8];    // kc_loc = 0
  #pragma unroll
  for (int d = 0; d < 3; ++d) {
    Bf[d][0] = *(const bf16x8*)(Bb0 + (long)d*2048);
    Bf[d][1] = *(const bf16x8*)(Bb1 + (long)d*2048);
  }

  for (int jj = 0; jj < 8; ++jj) {
    const int KL0 = jj*4;
    STEPM(0, 1, KL0+0, 0);
    STEPM(1, 0, KL0+1, 1);
    STEPM(0, 1, KL0+2, 2);
    STEPM(1, 0, KL0+3, 3);
  }

  if (q == 0) {                                   // fold +32*b2[h] once
    #pragma unroll
    for (int ht = 0; ht < 2; ++ht) {
      float bv = 32.0f * b2[(w*2 + ht)*16 + lr];
      #pragma unroll
      for (int r=0; r<4; ++r) acc2[ht][r] += bv;
    }
  }

  // C-layout: col(lr)=h within tile, row(lq*4+r)=b_loc (valid rows < 8)
  if (lq < 2) {
    #pragma unroll
    for (int ht = 0; ht < 2; ++ht) {
      int h = (w*2 + ht)*16 + lr;
      #pragma unroll
      for (int r=0; r<4; ++r) {
        int b = grp*8 + lq*4 + r;
        atomicAdd(&out[b*256 + 128 + h], acc2[ht][r]);
      }
    }
  }
}

// ---------------- launch ----------------
extern "C" void kernel_launch(void* const* d_in, const int* in_sizes, int n_in,
                              void* d_out, int out_size, void* d_ws, size_t ws_size,
                              hipStream_t stream) {
  const float* in = (const float*)d_in[0];
  const float* W1 = (const float*)d_in[1];
  const float* b1 = (const float*)d_in[2];
  const float* W2 = (const float*)d_in[3];
  const float* b2 = (const float*)d_in[4];
  float* out = (float*)d_out;

  char* ws = (char*)d_ws;
  bf16* w1q  = (bf16*)(ws);                 // 4*27*1024*2  = 221,184
  bf16* w2t2 = (bf16*)(ws + 1048576);       // 2*130*2048*2 = 1,064,960

  prep_all<<<628,  256, 0, stream>>>(W1, W2, w1q, w2t2);
  cinfuse <<<1024, 256, 0, stream>>>(in, w1q, w2t2, b1, b2, out);
}

// Round 14
// 96.183 us; speedup vs baseline: 1.0148x; 1.0148x over previous
//
#include <hip/hip_runtime.h>

typedef __bf16 bf16;
typedef __bf16 bf16x8 __attribute__((ext_vector_type(8)));
typedef __bf16 bf16x4 __attribute__((ext_vector_type(4)));
typedef float f32x4 __attribute__((ext_vector_type(4)));
typedef unsigned int u32;

#define NB    2048
#define NM    26
#define NJP   27      // 26 K-chunks + 1 zero pad (unconditional prefetch)

__device__ __forceinline__ void gl_lds16(const bf16* g, bf16* l) {
  __builtin_amdgcn_global_load_lds(
      (const __attribute__((address_space(1))) void*)g,
      (__attribute__((address_space(3))) void*)l, 16, 0, 0);
}

// ---------------- prep: frag-linear weight tiles (w1t + w2t2) ----------------
// In a 64x32 tile, element (r=ni*16+lr, c=lq*8+el) lives at
// ni*512 + lq*128 + lr*8 + el.  643,072 elems = 628 blocks * 256 * 4 exactly.
__global__ __launch_bounds__(256) void prep_all(
    const float* __restrict__ W1, const float* __restrict__ W2,
    bf16* __restrict__ w1t, bf16* __restrict__ w2t2)
{
  const int bid = blockIdx.x, t = threadIdx.x;
  #pragma unroll
  for (int g = 0; g < 4; ++g) {
    int ge = g*160768 + bid*256 + t;
    if (ge < 110592) {                    // w1t tiles [cs(2)][c(NJP)], frag-linear
      int e = ge;
      int el = e & 7, lr = (e >> 3) & 15, lq = (e >> 7) & 3, ni = (e >> 9) & 3;
      int rest = e >> 11;
      int c = rest % NJP, cs_idx = rest / NJP;
      int h = cs_idx*64 + ni*16 + lr;
      int i = lq*8 + el;
      float v = (i < NM && c < NM) ? W1[h*(NM*NM) + i*NM + c] : 0.f;
      w1t[e] = (bf16)v;
    } else {                              // w2t2 tiles [cs2(2)][kc(130)], frag-linear
      int e = ge - 110592;                // flatK = kc*32 + c  (kc=i, c=j)
      int el = e & 7, lr = (e >> 3) & 15, lq = (e >> 7) & 3, ni = (e >> 9) & 3;
      int rest = e >> 11;                 // [0, 260)
      int kc = rest % 130, cs_idx = rest / 130;
      int h = cs_idx*64 + ni*16 + lr;
      int c = lq*8 + el;
      float v = (kc < 128 && c < NM) ? W2[h*(128*NM) + kc*NM + c] : 0.f;
      w2t2[e] = (bf16)v;
    }
  }
}

// layer-1 K-chunk step, LDS-staged (r0-proven pattern): barrier; issue
// global_load_lds of chunk J+1 into buf NXT (one 16B op/thread = 4KB chunk,
// shared by all 4 waves); prefetch f32 scalars; read B-frags of chunk J from
// buf CUR via ds_read_b128; 16 MFMAs. Removes the 4x redundant per-wave L2
// reads of block-uniform w1t data.
#define STEPL(CUR, NXT, J) do {                                                \
  __syncthreads();                                                             \
  gl_lds16(tbg + (long)((J)+1)*2048 + t*8, &ldsB[NXT][t*8]);                   \
  { int jn = ((J)+1 > 25) ? 25 : (J)+1;  /* chunk-26 weights are zero */       \
    scf[NXT][0][0] = spw0[jn*32];  scf[NXT][0][1] = spw0[jn*32 + 16];          \
    scf[NXT][1][0] = spw1[jn*32];  scf[NXT][1][1] = spw1[jn*32 + 16]; }        \
  bf16x8 bfr[4];                                                               \
  _Pragma("unroll")                                                            \
  for (int ni = 0; ni < 4; ++ni)                                               \
    bfr[ni] = *(const bf16x8*)&ldsB[CUR][ni*512 + fo];                         \
  _Pragma("unroll")                                                            \
  for (int bb = 0; bb < 2; ++bb)                                               \
    _Pragma("unroll")                                                          \
    for (int mi = 0; mi < 2; ++mi) {                                           \
      bf16x8 af;                                                               \
      _Pragma("unroll")                                                        \
      for (int e = 0; e < 8; ++e)                                              \
        af[e] = (bf16)(xf32[bb][mi][e] * scf[CUR][bb][mi]);                    \
      _Pragma("unroll")                                                        \
      for (int ni = 0; ni < 4; ++ni)                                           \
        acc[bb][mi][ni] = __builtin_amdgcn_mfma_f32_16x16x32_bf16(af,          \
                                    bfr[ni], acc[bb][mi][ni], 0, 0, 0);        \
    }                                                                          \
} while (0)

// mini-gemm K-step: A (LDS, ping-pong) + B (w2t2 L2, 4-deep cyclic, literal
// phases). Tail prefetches read ldsU pad slots / mapped w2t2 overrun (unused).
#define STEPM(CA, NA, KL, Q) do {                                              \
  Af[NA] = *(const bf16x8*)&ldsU[(((KL)+1)*4 + lq)*72 + lr*8];                 \
  Bf[((Q)+3)&3][0] = *(const bf16x8*)(Bb0 + (long)((KL)+3)*2048);              \
  Bf[((Q)+3)&3][1] = *(const bf16x8*)(Bb1 + (long)((KL)+3)*2048);              \
  _Pragma("unroll")                                                            \
  for (int ht = 0; ht < 2; ++ht)                                               \
    acc2[ht] = __builtin_amdgcn_mfma_f32_16x16x32_bf16(Af[CA], Bf[(Q)][ht],    \
                                                       acc2[ht], 0, 0, 0);     \
} while (0)

// ---------------- fused: layer 1 + G (LDS) + layer-2 mini-gemm ---------------
// Block = 8 batches x one cs-half (r12 structure). LDS: ldsB[2][2048] staging
// dbuf (8 KB) + 38 KB ldsU union {phase A: 4 wave-private x1^T tiles [64][36];
// phase B: G A-tile ldsG[k8(256+8 pad)][b(8)][8], slot stride 72}. ag/bg carried
// across the repurposing barrier in registers. Mini-gemm: out2[8b x 32h] per
// wave-h-tile over K=2048, A from LDS, B 4-deep from w2t2. cs==0 folds bias.
__global__ __launch_bounds__(256, 3) void cinfuse(
    const float* __restrict__ in, const bf16* __restrict__ w1t,
    const bf16* __restrict__ w2t2, const float* __restrict__ b1,
    const float* __restrict__ b2, float* __restrict__ out)
{
  __shared__ __align__(16) bf16 ldsB[2][2048];    //  8,192 B (w1 chunk dbuf)
  __shared__ __align__(16) bf16 ldsU[264*72];     // 38,016 B (union, see above)
  const int t = threadIdx.x, bid = blockIdx.x;
  const int lane = t & 63, w = t >> 6;
  const int lr = lane & 15, lq = lane >> 4;
  const int fo = lq*128 + lr*8;
  const int cs_idx = bid & 1, cs = cs_idx * 64;
  const int grp = bid >> 1;                       // 0..255, 8 batches each
  const int bw0 = grp*8 + w*2;                    // this wave's batches bw0, bw0+1

  const float* bin0 = in + (long)bw0*(NM*32);
  const float* bin1 = bin0 + NM*32;
  const float* spw0 = bin0 + lr;                  // + j*32 + mi*16 (k = mi*16+lr)
  const float* spw1 = bin1 + lr;

  // x0 A-frags in f32: xf32[bb][mi][e] = x0[bw0+bb][j=lq*8+e][k=mi*16+lr]
  float xf32[2][2][8];
  #pragma unroll
  for (int bb = 0; bb < 2; ++bb) {
    const float* bin = bb ? bin1 : bin0;
    #pragma unroll
    for (int mi = 0; mi < 2; ++mi)
      #pragma unroll
      for (int e = 0; e < 8; ++e) {
        int j = lq*8 + e;
        xf32[bb][mi][e] = (j < NM) ? bin[j*32 + mi*16 + lr] : 0.f;
      }
  }

  f32x4 acc[2][2][4];
  #pragma unroll
  for (int bb=0; bb<2; ++bb)
    #pragma unroll
    for (int mi=0; mi<2; ++mi)
      #pragma unroll
      for (int ni=0; ni<4; ++ni) acc[bb][mi][ni] = {0.f,0.f,0.f,0.f};

  const bf16* tbg = w1t + (long)cs_idx*NJP*2048;  // block-uniform tile base

  float scf[2][2][2];
  gl_lds16(tbg + t*8, &ldsB[0][t*8]);             // stage chunk 0
  scf[0][0][0] = spw0[0];  scf[0][0][1] = spw0[16];
  scf[0][1][0] = spw1[0];  scf[0][1][1] = spw1[16];

  for (int jj = 0; jj < 13; ++jj) {
    STEPL(0, 1, 2*jj);
    STEPL(1, 0, 2*jj + 1);
  }

  float bias[4];
  #pragma unroll
  for (int ni=0; ni<4; ++ni) bias[ni] = b1[cs + ni*16 + lr];

  bf16* T = &ldsU[w*2304];                        // wave-private x1^T [64][36]

  bf16x8 agr[2][4];                               // held across the barrier
  bf16x8 bgr[2][2];

  #pragma unroll
  for (int bb = 0; bb < 2; ++bb) {
    const int bw = bw0 + bb;
    const float* bin = bb ? bin1 : bin0;

    // out[bw][cs:cs+64] = k-sum of x1 + 32*bias
    #pragma unroll
    for (int ni=0; ni<4; ++ni) {
      float vv = 0.f;
      #pragma unroll
      for (int mi=0; mi<2; ++mi)
        #pragma unroll
        for (int r=0; r<4; ++r) vv += acc[bb][mi][ni][r];
      vv += __shfl_xor(vv, 16, 64);
      vv += __shfl_xor(vv, 32, 64);
      if (lq == 0) out[bw*256 + cs + ni*16 + lr] = vv + 32.0f * bias[ni];
    }

    // x1 (C-layout) -> wave-private x1^T tile [i_local][k], row stride 36
    #pragma unroll
    for (int mi=0; mi<2; ++mi)
      #pragma unroll
      for (int ni=0; ni<4; ++ni) {
        bf16x4 pk;
        #pragma unroll
        for (int r=0; r<4; ++r) pk[r] = (bf16)(acc[bb][mi][ni][r] + bias[ni]);
        *(bf16x4*)&T[(ni*16+lr)*36 + mi*16 + lq*4] = pk;
      }
    // same-wave DS ordering: reads below see this wave's writes

    // A-frags of x1^T -> registers (survive the LDS repurposing barrier)
    #pragma unroll
    for (int mt = 0; mt < 4; ++mt)
      agr[bb][mt] = *(const bf16x8*)&T[(mt*16+lr)*36 + lq*8];

    // B-frags: x0[j][k] from in -> registers
    #pragma unroll
    for (int nt = 0; nt < 2; ++nt) {
      int j = nt*16 + lr;
      bf16x8 vv;
      #pragma unroll
      for (int e=0; e<8; ++e) vv[e] = (bf16)0.f;
      if (j < NM) {
        const float* src = bin + j*32 + lq*8;
        f32x4 a = *(const f32x4*)src, c = *(const f32x4*)(src+4);
        #pragma unroll
        for (int e=0; e<4; ++e) { vv[e] = (bf16)a[e]; vv[4+e] = (bf16)c[e]; }
      }
      bgr[bb][nt] = vv;
    }
  }

  __syncthreads();            // all x1^T reads done -> ldsU becomes the G-tile

  // swapped G-MFMAs; G goes to the LDS A-tile (local i, padded slots)
  #pragma unroll
  for (int bb = 0; bb < 2; ++bb) {
    const int bloc = w*2 + bb;                    // block-local batch 0..7
    #pragma unroll
    for (int mt = 0; mt < 4; ++mt) {
      #pragma unroll
      for (int nt = 0; nt < 2; ++nt) {
        f32x4 z = {0.f,0.f,0.f,0.f};
        f32x4 g = __builtin_amdgcn_mfma_f32_16x16x32_bf16(bgr[bb][nt],
                                                          agr[bb][mt], z, 0, 0, 0);
        // lane holds G[bw][i_loc=mt*16+lr][j=nt*16+lq*4+r]
        bf16x4 pk;
        #pragma unroll
        for (int r = 0; r < 4; ++r) pk[r] = (bf16)g[r];
        const int kh = (mt*16 + lr)*4 + nt*2 + (lq >> 1);   // flatK_loc >> 3
        *(bf16x4*)&ldsU[kh*72 + bloc*8 + (lq & 1)*4] = pk;
      }
    }
  }

  __syncthreads();                                // all 8 batches' G in ldsU

  // ---- mini-gemm: wave w owns h-tiles {w*2, w*2+1}; K = 2048 (64 kc) ----
  const int ht0 = w*2, ht1 = w*2 + 1;
  const bf16* Bb0 = w2t2 + ((long)(ht0 >> 2)*130 + cs)*2048 + (ht0 & 3)*512 + fo;
  const bf16* Bb1 = w2t2 + ((long)(ht1 >> 2)*130 + cs)*2048 + (ht1 & 3)*512 + fo;

  f32x4 acc2[2];
  acc2[0] = {0.f,0.f,0.f,0.f};  acc2[1] = {0.f,0.f,0.f,0.f};

  bf16x8 Af[2], Bf[4][2];
  Af[0] = *(const bf16x8*)&ldsU[lq*72 + lr*8];    // kc_loc = 0
  #pragma unroll
  for (int d = 0; d < 3; ++d) {
    Bf[d][0] = *(const bf16x8*)(Bb0 + (long)d*2048);
    Bf[d][1] = *(const bf16x8*)(Bb1 + (long)d*2048);
  }

  for (int jj = 0; jj < 16; ++jj) {
    const int KL0 = jj*4;
    STEPM(0, 1, KL0+0, 0);
    STEPM(1, 0, KL0+1, 1);
    STEPM(0, 1, KL0+2, 2);
    STEPM(1, 0, KL0+3, 3);
  }

  if (cs_idx == 0) {                              // fold +32*b2[h] once
    #pragma unroll
    for (int ht = 0; ht < 2; ++ht) {
      float bv = 32.0f * b2[(w*2 + ht)*16 + lr];
      #pragma unroll
      for (int r=0; r<4; ++r) acc2[ht][r] += bv;
    }
  }

  // C-layout: col(lr)=h within tile, row(lq*4+r)=b_loc (valid rows < 8)
  if (lq < 2) {
    #pragma unroll
    for (int ht = 0; ht < 2; ++ht) {
      int h = (w*2 + ht)*16 + lr;
      #pragma unroll
      for (int r=0; r<4; ++r) {
        int b = grp*8 + lq*4 + r;
        atomicAdd(&out[b*256 + 128 + h], acc2[ht][r]);
      }
    }
  }
}

// ---------------- launch ----------------
extern "C" void kernel_launch(void* const* d_in, const int* in_sizes, int n_in,
                              void* d_out, int out_size, void* d_ws, size_t ws_size,
                              hipStream_t stream) {
  const float* in = (const float*)d_in[0];
  const float* W1 = (const float*)d_in[1];
  const float* b1 = (const float*)d_in[2];
  const float* W2 = (const float*)d_in[3];
  const float* b2 = (const float*)d_in[4];
  float* out = (float*)d_out;

  char* ws = (char*)d_ws;
  bf16* w1t  = (bf16*)(ws);                 // 2*27*2048*2  = 221,184
  bf16* w2t2 = (bf16*)(ws + 1048576);       // 2*130*2048*2 = 1,064,960

  prep_all<<<628, 256, 0, stream>>>(W1, W2, w1t, w2t2);
  cinfuse <<<512, 256, 0, stream>>>(in, w1t, w2t2, b1, b2, out);
}

// Round 15
// 93.443 us; speedup vs baseline: 1.0445x; 1.0293x over previous
//
#include <hip/hip_runtime.h>

typedef __bf16 bf16;
typedef __bf16 bf16x8 __attribute__((ext_vector_type(8)));
typedef __bf16 bf16x4 __attribute__((ext_vector_type(4)));
typedef float f32x4 __attribute__((ext_vector_type(4)));
typedef unsigned int u32;

#define NB    2048
#define NM    26
#define NJP   27      // 26 K-chunks + 1 zero pad (unconditional prefetch)
#define GS    76      // ldsG slot stride (elems): 4-way write banks, not 8-way

// ---------------- prep: frag-linear weight tiles (w1t + w2t2) ----------------
// In a 64x32 tile, element (r=ni*16+lr, c=lq*8+el) lives at
// ni*512 + lq*128 + lr*8 + el.  643,072 elems = 628 blocks * 256 * 4 exactly.
__global__ __launch_bounds__(256) void prep_all(
    const float* __restrict__ W1, const float* __restrict__ W2,
    bf16* __restrict__ w1t, bf16* __restrict__ w2t2)
{
  const int bid = blockIdx.x, t = threadIdx.x;
  #pragma unroll
  for (int g = 0; g < 4; ++g) {
    int ge = g*160768 + bid*256 + t;
    if (ge < 110592) {                    // w1t tiles [cs(2)][c(NJP)], frag-linear
      int e = ge;
      int el = e & 7, lr = (e >> 3) & 15, lq = (e >> 7) & 3, ni = (e >> 9) & 3;
      int rest = e >> 11;
      int c = rest % NJP, cs_idx = rest / NJP;
      int h = cs_idx*64 + ni*16 + lr;
      int i = lq*8 + el;
      float v = (i < NM && c < NM) ? W1[h*(NM*NM) + i*NM + c] : 0.f;
      w1t[e] = (bf16)v;
    } else {                              // w2t2 tiles [cs2(2)][kc(130)], frag-linear
      int e = ge - 110592;                // flatK = kc*32 + c  (kc=i, c=j)
      int el = e & 7, lr = (e >> 3) & 15, lq = (e >> 7) & 3, ni = (e >> 9) & 3;
      int rest = e >> 11;                 // [0, 260)
      int kc = rest % 130, cs_idx = rest / 130;
      int h = cs_idx*64 + ni*16 + lr;
      int c = lq*8 + el;
      float v = (kc < 128 && c < NM) ? W2[h*(128*NM) + kc*NM + c] : 0.f;
      w2t2[e] = (bf16)v;
    }
  }
}

// layer-1 K-chunk step: scalars (f32) + B-frags prefetched 1 ahead; compute
// chunk J for BOTH batches from buffer CUR. af built in f32 then converted.
#define STEP(CUR, NXT, J) do {                                                 \
  { int jn = ((J)+1 > 25) ? 25 : (J)+1;  /* chunk-26 weights are zero */       \
    scf[NXT][0][0] = spw0[jn*32];  scf[NXT][0][1] = spw0[jn*32 + 16];          \
    scf[NXT][1][0] = spw1[jn*32];  scf[NXT][1][1] = spw1[jn*32 + 16]; }        \
  _Pragma("unroll")                                                            \
  for (int ni = 0; ni < 4; ++ni)                                               \
    B[NXT][ni] = *(const bf16x8*)(tb + (long)((J)+1)*2048 + ni*512);           \
  _Pragma("unroll")                                                            \
  for (int bb = 0; bb < 2; ++bb)                                               \
    _Pragma("unroll")                                                          \
    for (int mi = 0; mi < 2; ++mi) {                                           \
      bf16x8 af;                                                               \
      _Pragma("unroll")                                                        \
      for (int e = 0; e < 8; ++e)                                              \
        af[e] = (bf16)(xf32[bb][mi][e] * scf[CUR][bb][mi]);                    \
      _Pragma("unroll")                                                        \
      for (int ni = 0; ni < 4; ++ni)                                           \
        acc[bb][mi][ni] = __builtin_amdgcn_mfma_f32_16x16x32_bf16(af,          \
                                    B[CUR][ni], acc[bb][mi][ni], 0, 0, 0);     \
    }                                                                          \
} while (0)

// mini-gemm K-step: A (LDS, ping-pong) + B (w2t2 L2, 4-deep cyclic, literal
// phases). Tail prefetches read ldsU pad slots / mapped w2t2 overrun (unused).
#define STEPM(CA, NA, KL, Q) do {                                              \
  Af[NA] = *(const bf16x8*)&ldsU[(((KL)+1)*4 + lq)*GS + lr*8];                 \
  Bf[((Q)+3)&3][0] = *(const bf16x8*)(Bb0 + (long)((KL)+3)*2048);              \
  Bf[((Q)+3)&3][1] = *(const bf16x8*)(Bb1 + (long)((KL)+3)*2048);              \
  _Pragma("unroll")                                                            \
  for (int ht = 0; ht < 2; ++ht)                                               \
    acc2[ht] = __builtin_amdgcn_mfma_f32_16x16x32_bf16(Af[CA], Bf[(Q)][ht],    \
                                                       acc2[ht], 0, 0, 0);     \
} while (0)

// ---------------- fused: layer 1 + G (LDS) + layer-2 mini-gemm ---------------
// Block = 8 batches x one cs-half. LDS is a 40.1 KB UNION with two lifetimes:
// phase A = 4 wave-private x1^T tiles [64][36] (9,216 elems), phase B = padded
// G A-tile ldsG[k8(256+8 pad)][b(8)][8] (slot stride GS=76: G-write banks
// spread 4-way; A-read stays 2-way-free). Phases separated by a barrier
// (ag/bg held in registers across it). 3 blocks/CU cap, grid 512 = 2 resident.
// Mini-gemm: out2[8b x 32h] over K=2048, A from LDS, B 4-deep from w2t2.
__global__ __launch_bounds__(256, 3) void cinfuse(
    const float* __restrict__ in, const bf16* __restrict__ w1t,
    const bf16* __restrict__ w2t2, const float* __restrict__ b1,
    const float* __restrict__ b2, float* __restrict__ out)
{
  __shared__ __align__(16) bf16 ldsU[264*GS];     // 40,128 B (union, see above)
  const int t = threadIdx.x, bid = blockIdx.x;
  const int lane = t & 63, w = t >> 6;
  const int lr = lane & 15, lq = lane >> 4;
  const int fo = lq*128 + lr*8;
  const int cs_idx = bid & 1, cs = cs_idx * 64;
  const int grp = bid >> 1;                       // 0..255, 8 batches each
  const int bw0 = grp*8 + w*2;                    // this wave's batches bw0, bw0+1

  const float* bin0 = in + (long)bw0*(NM*32);
  const float* bin1 = bin0 + NM*32;
  const float* spw0 = bin0 + lr;                  // + j*32 + mi*16 (k = mi*16+lr)
  const float* spw1 = bin1 + lr;

  // x0 A-frags in f32: xf32[bb][mi][e] = x0[bw0+bb][j=lq*8+e][k=mi*16+lr]
  float xf32[2][2][8];
  #pragma unroll
  for (int bb = 0; bb < 2; ++bb) {
    const float* bin = bb ? bin1 : bin0;
    #pragma unroll
    for (int mi = 0; mi < 2; ++mi)
      #pragma unroll
      for (int e = 0; e < 8; ++e) {
        int j = lq*8 + e;
        xf32[bb][mi][e] = (j < NM) ? bin[j*32 + mi*16 + lr] : 0.f;
      }
  }

  f32x4 acc[2][2][4];
  #pragma unroll
  for (int bb=0; bb<2; ++bb)
    #pragma unroll
    for (int mi=0; mi<2; ++mi)
      #pragma unroll
      for (int ni=0; ni<4; ++ni) acc[bb][mi][ni] = {0.f,0.f,0.f,0.f};

  const bf16* tb = w1t + (long)cs_idx*NJP*2048 + fo;

  float scf[2][2][2];
  bf16x8 B[2][4];
  #pragma unroll
  for (int ni = 0; ni < 4; ++ni)
    B[0][ni] = *(const bf16x8*)(tb + ni*512);     // chunk 0
  scf[0][0][0] = spw0[0];  scf[0][0][1] = spw0[16];
  scf[0][1][0] = spw1[0];  scf[0][1][1] = spw1[16];

  for (int jj = 0; jj < 13; ++jj) {
    STEP(0, 1, 2*jj);
    STEP(1, 0, 2*jj + 1);
  }

  float bias[4];
  #pragma unroll
  for (int ni=0; ni<4; ++ni) bias[ni] = b1[cs + ni*16 + lr];

  bf16* T = &ldsU[w*2304];                        // wave-private x1^T [64][36]

  bf16x8 agr[2][4];                               // held across the barrier
  bf16x8 bgr[2][2];

  #pragma unroll
  for (int bb = 0; bb < 2; ++bb) {
    const int bw = bw0 + bb;
    const float* bin = bb ? bin1 : bin0;

    // out[bw][cs:cs+64] = k-sum of x1 + 32*bias
    #pragma unroll
    for (int ni=0; ni<4; ++ni) {
      float vv = 0.f;
      #pragma unroll
      for (int mi=0; mi<2; ++mi)
        #pragma unroll
        for (int r=0; r<4; ++r) vv += acc[bb][mi][ni][r];
      vv += __shfl_xor(vv, 16, 64);
      vv += __shfl_xor(vv, 32, 64);
      if (lq == 0) out[bw*256 + cs + ni*16 + lr] = vv + 32.0f * bias[ni];
    }

    // x1 (C-layout) -> wave-private x1^T tile [i_local][k], row stride 36
    #pragma unroll
    for (int mi=0; mi<2; ++mi)
      #pragma unroll
      for (int ni=0; ni<4; ++ni) {
        bf16x4 pk;
        #pragma unroll
        for (int r=0; r<4; ++r) pk[r] = (bf16)(acc[bb][mi][ni][r] + bias[ni]);
        *(bf16x4*)&T[(ni*16+lr)*36 + mi*16 + lq*4] = pk;
      }
    // same-wave DS ordering: reads below see this wave's writes

    // A-frags of x1^T -> registers (survive the LDS repurposing barrier)
    #pragma unroll
    for (int mt = 0; mt < 4; ++mt)
      agr[bb][mt] = *(const bf16x8*)&T[(mt*16+lr)*36 + lq*8];

    // B-frags: x0[j][k] from in -> registers
    #pragma unroll
    for (int nt = 0; nt < 2; ++nt) {
      int j = nt*16 + lr;
      bf16x8 vv;
      #pragma unroll
      for (int e=0; e<8; ++e) vv[e] = (bf16)0.f;
      if (j < NM) {
        const float* src = bin + j*32 + lq*8;
        f32x4 a = *(const f32x4*)src, c = *(const f32x4*)(src+4);
        #pragma unroll
        for (int e=0; e<4; ++e) { vv[e] = (bf16)a[e]; vv[4+e] = (bf16)c[e]; }
      }
      bgr[bb][nt] = vv;
    }
  }

  __syncthreads();            // all x1^T reads done -> ldsU becomes the G-tile

  // swapped G-MFMAs; G goes to the LDS A-tile (local i, padded slots)
  #pragma unroll
  for (int bb = 0; bb < 2; ++bb) {
    const int bloc = w*2 + bb;                    // block-local batch 0..7
    #pragma unroll
    for (int mt = 0; mt < 4; ++mt) {
      #pragma unroll
      for (int nt = 0; nt < 2; ++nt) {
        f32x4 z = {0.f,0.f,0.f,0.f};
        f32x4 g = __builtin_amdgcn_mfma_f32_16x16x32_bf16(bgr[bb][nt],
                                                          agr[bb][mt], z, 0, 0, 0);
        // lane holds G[bw][i_loc=mt*16+lr][j=nt*16+lq*4+r]
        bf16x4 pk;
        #pragma unroll
        for (int r = 0; r < 4; ++r) pk[r] = (bf16)g[r];
        const int kh = (mt*16 + lr)*4 + nt*2 + (lq >> 1);   // flatK_loc >> 3
        *(bf16x4*)&ldsU[kh*GS + bloc*8 + (lq & 1)*4] = pk;
      }
    }
  }

  __syncthreads();                                // all 8 batches' G in ldsU

  // ---- mini-gemm: wave w owns h-tiles {w*2, w*2+1}; K = 2048 (64 kc) ----
  const int ht0 = w*2, ht1 = w*2 + 1;
  const bf16* Bb0 = w2t2 + ((long)(ht0 >> 2)*130 + cs)*2048 + (ht0 & 3)*512 + fo;
  const bf16* Bb1 = w2t2 + ((long)(ht1 >> 2)*130 + cs)*2048 + (ht1 & 3)*512 + fo;

  f32x4 acc2[2];
  acc2[0] = {0.f,0.f,0.f,0.f};  acc2[1] = {0.f,0.f,0.f,0.f};

  bf16x8 Af[2], Bf[4][2];
  Af[0] = *(const bf16x8*)&ldsU[lq*GS + lr*8];    // kc_loc = 0
  #pragma unroll
  for (int d = 0; d < 3; ++d) {
    Bf[d][0] = *(const bf16x8*)(Bb0 + (long)d*2048);
    Bf[d][1] = *(const bf16x8*)(Bb1 + (long)d*2048);
  }

  for (int jj = 0; jj < 16; ++jj) {
    const int KL0 = jj*4;
    STEPM(0, 1, KL0+0, 0);
    STEPM(1, 0, KL0+1, 1);
    STEPM(0, 1, KL0+2, 2);
    STEPM(1, 0, KL0+3, 3);
  }

  if (cs_idx == 0) {                              // fold +32*b2[h] once
    #pragma unroll
    for (int ht = 0; ht < 2; ++ht) {
      float bv = 32.0f * b2[(w*2 + ht)*16 + lr];
      #pragma unroll
      for (int r=0; r<4; ++r) acc2[ht][r] += bv;
    }
  }

  // C-layout: col(lr)=h within tile, row(lq*4+r)=b_loc (valid rows < 8)
  if (lq < 2) {
    #pragma unroll
    for (int ht = 0; ht < 2; ++ht) {
      int h = (w*2 + ht)*16 + lr;
      #pragma unroll
      for (int r=0; r<4; ++r) {
        int b = grp*8 + lq*4 + r;
        atomicAdd(&out[b*256 + 128 + h], acc2[ht][r]);
      }
    }
  }
}

// ---------------- launch ----------------
extern "C" void kernel_launch(void* const* d_in, const int* in_sizes, int n_in,
                              void* d_out, int out_size, void* d_ws, size_t ws_size,
                              hipStream_t stream) {
  const float* in = (const float*)d_in[0];
  const float* W1 = (const float*)d_in[1];
  const float* b1 = (const float*)d_in[2];
  const float* W2 = (const float*)d_in[3];
  const float* b2 = (const float*)d_in[4];
  float* out = (float*)d_out;

  char* ws = (char*)d_ws;
  bf16* w1t  = (bf16*)(ws);                 // 2*27*2048*2  = 221,184
  bf16* w2t2 = (bf16*)(ws + 1048576);       // 2*130*2048*2 = 1,064,960

  prep_all<<<628, 256, 0, stream>>>(W1, W2, w1t, w2t2);
  cinfuse <<<512, 256, 0, stream>>>(in, w1t, w2t2, b1, b2, out);
}

// Round 18
// 93.230 us; speedup vs baseline: 1.0469x; 1.0023x over previous
//
#include <hip/hip_runtime.h>

typedef __bf16 bf16;
typedef __bf16 bf16x8 __attribute__((ext_vector_type(8)));
typedef __bf16 bf16x4 __attribute__((ext_vector_type(4)));
typedef float f32x4 __attribute__((ext_vector_type(4)));
typedef unsigned int u32;

#define NB    2048
#define NM    26
#define NJP   27      // 26 K-chunks + 1 zero pad (unconditional prefetch)

// ---------------- prep: frag-linear weight tiles (w1t + w2t2) ----------------
// In a 64x32 tile, element (r=ni*16+lr, c=lq*8+el) lives at
// ni*512 + lq*128 + lr*8 + el.  643,072 elems = 628 blocks * 256 * 4 exactly.
__global__ __launch_bounds__(256) void prep_all(
    const float* __restrict__ W1, const float* __restrict__ W2,
    bf16* __restrict__ w1t, bf16* __restrict__ w2t2)
{
  const int bid = blockIdx.x, t = threadIdx.x;
  #pragma unroll
  for (int g = 0; g < 4; ++g) {
    int ge = g*160768 + bid*256 + t;
    if (ge < 110592) {                    // w1t tiles [cs(2)][c(NJP)], frag-linear
      int e = ge;
      int el = e & 7, lr = (e >> 3) & 15, lq = (e >> 7) & 3, ni = (e >> 9) & 3;
      int rest = e >> 11;
      int c = rest % NJP, cs_idx = rest / NJP;
      int h = cs_idx*64 + ni*16 + lr;
      int i = lq*8 + el;
      float v = (i < NM && c < NM) ? W1[h*(NM*NM) + i*NM + c] : 0.f;
      w1t[e] = (bf16)v;
    } else {                              // w2t2 tiles [cs2(2)][kc(130)], frag-linear
      int e = ge - 110592;                // flatK = kc*32 + c  (kc=i, c=j)
      int el = e & 7, lr = (e >> 3) & 15, lq = (e >> 7) & 3, ni = (e >> 9) & 3;
      int rest = e >> 11;                 // [0, 260)
      int kc = rest % 130, cs_idx = rest / 130;
      int h = cs_idx*64 + ni*16 + lr;
      int c = lq*8 + el;
      float v = (kc < 128 && c < NM) ? W2[h*(128*NM) + kc*NM + c] : 0.f;
      w2t2[e] = (bf16)v;
    }
  }
}

// layer-1 K-chunk step: scalars (f32) + B-frags prefetched 1 ahead; compute
// chunk J for BOTH batches from buffer CUR. af built in f32 then converted.
#define STEP(CUR, NXT, J) do {                                                 \
  { int jn = ((J)+1 > 25) ? 25 : (J)+1;  /* chunk-26 weights are zero */       \
    scf[NXT][0][0] = spw0[jn*32];  scf[NXT][0][1] = spw0[jn*32 + 16];          \
    scf[NXT][1][0] = spw1[jn*32];  scf[NXT][1][1] = spw1[jn*32 + 16]; }        \
  _Pragma("unroll")                                                            \
  for (int ni = 0; ni < 4; ++ni)                                               \
    B[NXT][ni] = *(const bf16x8*)(tb + (long)((J)+1)*2048 + ni*512);           \
  _Pragma("unroll")                                                            \
  for (int bb = 0; bb < 2; ++bb)                                               \
    _Pragma("unroll")                                                          \
    for (int mi = 0; mi < 2; ++mi) {                                           \
      bf16x8 af;                                                               \
      _Pragma("unroll")                                                        \
      for (int e = 0; e < 8; ++e)                                              \
        af[e] = (bf16)(xf32[bb][mi][e] * scf[CUR][bb][mi]);                    \
      _Pragma("unroll")                                                        \
      for (int ni = 0; ni < 4; ++ni)                                           \
        acc[bb][mi][ni] = __builtin_amdgcn_mfma_f32_16x16x32_bf16(af,          \
                                    B[CUR][ni], acc[bb][mi][ni], 0, 0, 0);     \
    }                                                                          \
} while (0)

// mini-gemm K-step: A (LDS, ping-pong) + B (w2t2 L2, 4-deep cyclic, literal
// phases). Tail prefetches read ldsU pad slots / mapped w2t2 overrun (unused).
#define STEPM(CA, NA, KL, Q) do {                                              \
  Af[NA] = *(const bf16x8*)&ldsU[(((KL)+1)*4 + lq)*72 + lr*8];                 \
  Bf[((Q)+3)&3][0] = *(const bf16x8*)(Bb0 + (long)((KL)+3)*2048);              \
  Bf[((Q)+3)&3][1] = *(const bf16x8*)(Bb1 + (long)((KL)+3)*2048);              \
  _Pragma("unroll")                                                            \
  for (int ht = 0; ht < 2; ++ht)                                               \
    acc2[ht] = __builtin_amdgcn_mfma_f32_16x16x32_bf16(Af[CA], Bf[(Q)][ht],    \
                                                       acc2[ht], 0, 0, 0);     \
} while (0)

// ---------------- fused: layer 1 + G (LDS) + layer-2 mini-gemm ---------------
// Block = 8 batches x one cs-half. LDS is a 38 KB UNION with two lifetimes:
// phase A = 4 wave-private x1^T tiles (9,216 elems used), phase B = padded
// G A-tile ldsG[k8(256+8 pad)][b(8)][8] (slot stride 72). Phases separated
// by a barrier (ag/bg held in registers across it). Verified best (r12: 91.9).
// Mini-gemm: out2[8b x 32h] over K=2048, A from LDS, B 4-deep from w2t2.
__global__ __launch_bounds__(256, 3) void cinfuse(
    const float* __restrict__ in, const bf16* __restrict__ w1t,
    const bf16* __restrict__ w2t2, const float* __restrict__ b1,
    const float* __restrict__ b2, float* __restrict__ out)
{
  __shared__ __align__(16) bf16 ldsU[264*72];     // 38,016 B (union, see above)
  const int t = threadIdx.x, bid = blockIdx.x;
  const int lane = t & 63, w = t >> 6;
  const int lr = lane & 15, lq = lane >> 4;
  const int fo = lq*128 + lr*8;
  const int cs_idx = bid & 1, cs = cs_idx * 64;
  const int grp = bid >> 1;                       // 0..255, 8 batches each
  const int bw0 = grp*8 + w*2;                    // this wave's batches bw0, bw0+1

  const float* bin0 = in + (long)bw0*(NM*32);
  const float* bin1 = bin0 + NM*32;
  const float* spw0 = bin0 + lr;                  // + j*32 + mi*16 (k = mi*16+lr)
  const float* spw1 = bin1 + lr;

  // x0 A-frags in f32: xf32[bb][mi][e] = x0[bw0+bb][j=lq*8+e][k=mi*16+lr]
  float xf32[2][2][8];
  #pragma unroll
  for (int bb = 0; bb < 2; ++bb) {
    const float* bin = bb ? bin1 : bin0;
    #pragma unroll
    for (int mi = 0; mi < 2; ++mi)
      #pragma unroll
      for (int e = 0; e < 8; ++e) {
        int j = lq*8 + e;
        xf32[bb][mi][e] = (j < NM) ? bin[j*32 + mi*16 + lr] : 0.f;
      }
  }

  f32x4 acc[2][2][4];
  #pragma unroll
  for (int bb=0; bb<2; ++bb)
    #pragma unroll
    for (int mi=0; mi<2; ++mi)
      #pragma unroll
      for (int ni=0; ni<4; ++ni) acc[bb][mi][ni] = {0.f,0.f,0.f,0.f};

  const bf16* tb = w1t + (long)cs_idx*NJP*2048 + fo;

  float scf[2][2][2];
  bf16x8 B[2][4];
  #pragma unroll
  for (int ni = 0; ni < 4; ++ni)
    B[0][ni] = *(const bf16x8*)(tb + ni*512);     // chunk 0
  scf[0][0][0] = spw0[0];  scf[0][0][1] = spw0[16];
  scf[0][1][0] = spw1[0];  scf[0][1][1] = spw1[16];

  for (int jj = 0; jj < 13; ++jj) {
    STEP(0, 1, 2*jj);
    STEP(1, 0, 2*jj + 1);
  }

  float bias[4];
  #pragma unroll
  for (int ni=0; ni<4; ++ni) bias[ni] = b1[cs + ni*16 + lr];

  bf16* T = &ldsU[w*2304];                        // wave-private x1^T [64][36]

  bf16x8 agr[2][4];                               // held across the barrier
  bf16x8 bgr[2][2];

  #pragma unroll
  for (int bb = 0; bb < 2; ++bb) {
    const int bw = bw0 + bb;
    const float* bin = bb ? bin1 : bin0;

    // out[bw][cs:cs+64] = k-sum of x1 + 32*bias
    #pragma unroll
    for (int ni=0; ni<4; ++ni) {
      float vv = 0.f;
      #pragma unroll
      for (int mi=0; mi<2; ++mi)
        #pragma unroll
        for (int r=0; r<4; ++r) vv += acc[bb][mi][ni][r];
      vv += __shfl_xor(vv, 16, 64);
      vv += __shfl_xor(vv, 32, 64);
      if (lq == 0) out[bw*256 + cs + ni*16 + lr] = vv + 32.0f * bias[ni];
    }

    // x1 (C-layout) -> wave-private x1^T tile [i_local][k], row stride 36
    #pragma unroll
    for (int mi=0; mi<2; ++mi)
      #pragma unroll
      for (int ni=0; ni<4; ++ni) {
        bf16x4 pk;
        #pragma unroll
        for (int r=0; r<4; ++r) pk[r] = (bf16)(acc[bb][mi][ni][r] + bias[ni]);
        *(bf16x4*)&T[(ni*16+lr)*36 + mi*16 + lq*4] = pk;
      }
    // same-wave DS ordering: reads below see this wave's writes

    // A-frags of x1^T -> registers (survive the LDS repurposing barrier)
    #pragma unroll
    for (int mt = 0; mt < 4; ++mt)
      agr[bb][mt] = *(const bf16x8*)&T[(mt*16+lr)*36 + lq*8];

    // B-frags: x0[j][k] from in -> registers
    #pragma unroll
    for (int nt = 0; nt < 2; ++nt) {
      int j = nt*16 + lr;
      bf16x8 vv;
      #pragma unroll
      for (int e=0; e<8; ++e) vv[e] = (bf16)0.f;
      if (j < NM) {
        const float* src = bin + j*32 + lq*8;
        f32x4 a = *(const f32x4*)src, c = *(const f32x4*)(src+4);
        #pragma unroll
        for (int e=0; e<4; ++e) { vv[e] = (bf16)a[e]; vv[4+e] = (bf16)c[e]; }
      }
      bgr[bb][nt] = vv;
    }
  }

  __syncthreads();            // all x1^T reads done -> ldsU becomes the G-tile

  // swapped G-MFMAs; G goes to the LDS A-tile (local i, padded slots)
  #pragma unroll
  for (int bb = 0; bb < 2; ++bb) {
    const int bloc = w*2 + bb;                    // block-local batch 0..7
    #pragma unroll
    for (int mt = 0; mt < 4; ++mt) {
      #pragma unroll
      for (int nt = 0; nt < 2; ++nt) {
        f32x4 z = {0.f,0.f,0.f,0.f};
        f32x4 g = __builtin_amdgcn_mfma_f32_16x16x32_bf16(bgr[bb][nt],
                                                          agr[bb][mt], z, 0, 0, 0);
        // lane holds G[bw][i_loc=mt*16+lr][j=nt*16+lq*4+r]
        bf16x4 pk;
        #pragma unroll
        for (int r = 0; r < 4; ++r) pk[r] = (bf16)g[r];
        const int kh = (mt*16 + lr)*4 + nt*2 + (lq >> 1);   // flatK_loc >> 3
        *(bf16x4*)&ldsU[kh*72 + bloc*8 + (lq & 1)*4] = pk;
      }
    }
  }

  __syncthreads();                                // all 8 batches' G in ldsU

  // ---- mini-gemm: wave w owns h-tiles {w*2, w*2+1}; K = 2048 (64 kc) ----
  const int ht0 = w*2, ht1 = w*2 + 1;
  const bf16* Bb0 = w2t2 + ((long)(ht0 >> 2)*130 + cs)*2048 + (ht0 & 3)*512 + fo;
  const bf16* Bb1 = w2t2 + ((long)(ht1 >> 2)*130 + cs)*2048 + (ht1 & 3)*512 + fo;

  f32x4 acc2[2];
  acc2[0] = {0.f,0.f,0.f,0.f};  acc2[1] = {0.f,0.f,0.f,0.f};

  bf16x8 Af[2], Bf[4][2];
  Af[0] = *(const bf16x8*)&ldsU[lq*72 + lr*8];    // kc_loc = 0
  #pragma unroll
  for (int d = 0; d < 3; ++d) {
    Bf[d][0] = *(const bf16x8*)(Bb0 + (long)d*2048);
    Bf[d][1] = *(const bf16x8*)(Bb1 + (long)d*2048);
  }

  for (int jj = 0; jj < 16; ++jj) {
    const int KL0 = jj*4;
    STEPM(0, 1, KL0+0, 0);
    STEPM(1, 0, KL0+1, 1);
    STEPM(0, 1, KL0+2, 2);
    STEPM(1, 0, KL0+3, 3);
  }

  if (cs_idx == 0) {                              // fold +32*b2[h] once
    #pragma unroll
    for (int ht = 0; ht < 2; ++ht) {
      float bv = 32.0f * b2[(w*2 + ht)*16 + lr];
      #pragma unroll
      for (int r=0; r<4; ++r) acc2[ht][r] += bv;
    }
  }

  // C-layout: col(lr)=h within tile, row(lq*4+r)=b_loc (valid rows < 8)
  if (lq < 2) {
    #pragma unroll
    for (int ht = 0; ht < 2; ++ht) {
      int h = (w*2 + ht)*16 + lr;
      #pragma unroll
      for (int r=0; r<4; ++r) {
        int b = grp*8 + lq*4 + r;
        atomicAdd(&out[b*256 + 128 + h], acc2[ht][r]);
      }
    }
  }
}

// ---------------- launch ----------------
extern "C" void kernel_launch(void* const* d_in, const int* in_sizes, int n_in,
                              void* d_out, int out_size, void* d_ws, size_t ws_size,
                              hipStream_t stream) {
  const float* in = (const float*)d_in[0];
  const float* W1 = (const float*)d_in[1];
  const float* b1 = (const float*)d_in[2];
  const float* W2 = (const float*)d_in[3];
  const float* b2 = (const float*)d_in[4];
  float* out = (float*)d_out;

  char* ws = (char*)d_ws;
  bf16* w1t  = (bf16*)(ws);                 // 2*27*2048*2  = 221,184
  bf16* w2t2 = (bf16*)(ws + 1048576);       // 2*130*2048*2 = 1,064,960

  prep_all<<<628, 256, 0, stream>>>(W1, W2, w1t, w2t2);
  cinfuse <<<512, 256, 0, stream>>>(in, w1t, w2t2, b1, b2, out);
}